// Round 9
// baseline (1880.796 us; speedup 1.0000x reference)
//
#include <hip/hip_runtime.h>
#include <math.h>

#define GRID_N 512
#define IM_N   256
#define NCOIL  8
#define NK     131072
#define PLANE  (GRID_N*GRID_N)
#define JW     6
#define BETA_F 13.8551003f   /* pi*sqrt((6/2)^2*(2-0.5)^2 - 0.8) */
#define KSCALE 81.48733086305042f  /* 512/(2*pi) */

struct cplx { float x, y; };

__device__ __forceinline__ float bessel_i0f(float x){
  // Abramowitz & Stegun 9.8.1 / 9.8.2, rel err < 2e-7
  if (x < 3.75f){
    float t = x*(1.0f/3.75f); t = t*t;
    return 1.0f + t*(3.5156229f + t*(3.0899424f + t*(1.2067492f
           + t*(0.2659732f + t*(0.0360768f + t*0.0045813f)))));
  } else {
    float t = 3.75f/x;
    float p = 0.39894228f + t*(0.01328592f + t*(0.00225319f + t*(-0.00157565f
            + t*(0.00916281f + t*(-0.02057706f + t*(0.02635537f
            + t*(-0.01647633f + t*0.00392377f)))))));
    return p * __expf(x) * rsqrtf(x);
  }
}

__device__ __forceinline__ float kb_w(float u){   // 1-axis KB weight, |u|<=3
  float uu = u*(1.0f/3.0f);
  float q = fmaxf(1.0f - uu*uu, 0.0f);
  return bessel_i0f(BETA_F*sqrtf(q)) * (1.0f/6.0f);
}

__device__ __forceinline__ unsigned bf16_of(float f){
  unsigned u = __float_as_uint(f);
  return (u + 0x8000u) >> 16;                 // round-to-nearest-ish
}
__device__ __forceinline__ float bf_lo(unsigned w){ return __uint_as_float(w << 16); }
__device__ __forceinline__ float bf_hi(unsigned w){ return __uint_as_float(w & 0xFFFF0000u); }

// Kaiser-Bessel apodization correction row table sc[256]
__global__ void k_sc_table(float* sc){
  int i = threadIdx.x;
  if (i >= IM_N) return;
  float n  = (i - IM_N*0.5f) * (1.0f/GRID_N);
  float pj = 3.14159265358979f * (float)JW * n;
  float t  = BETA_F*BETA_F - pj*pj;
  float sp = sqrtf(fmaxf(t, 1e-12f));
  float sn = sqrtf(fmaxf(-t, 1e-12f));
  float ft = (t > 0.0f) ? (sinhf(sp)/sp) : (sinf(sn)/sn);
  float sc0 = sinhf(BETA_F)/BETA_F;
  sc[i] = sc0/ft;
}

__global__ void k_zero4(float4* p, int n4){
  int i = blockIdx.x*blockDim.x + threadIdx.x;
  if (i < n4) p[i] = make_float4(0.f,0.f,0.f,0.f);
}

__global__ void k_zero1(float* p, int n){
  int i = blockIdx.x*blockDim.x + threadIdx.x;
  if (i < n) p[i] = 0.f;
}

// coil_images * sc2 into padded 512^2 planar grids (A zeroed beforehand)
__global__ void k_fill(const float* __restrict__ ximg, const float* __restrict__ sr,
                       const float* __restrict__ si, const float* __restrict__ sc,
                       cplx* __restrict__ A){
  int idx = blockIdx.x*blockDim.x + threadIdx.x;   // c*65536 + y*256 + x
  if (idx >= NCOIL*IM_N*IM_N) return;
  int c = idx >> 16;
  int pix = idx & 65535;
  int y = pix >> 8, x = pix & 255;
  float v = ximg[pix] * sc[y]*sc[x];
  cplx o; o.x = v * sr[idx]; o.y = v * si[idx];
  A[(size_t)c*PLANE + y*GRID_N + x] = o;
}

// in-place 512-pt radix-2 FFT on each contiguous row; DIR=-1 fwd, +1 inv(unnorm)
template<int DIR>
__global__ void k_fft_rows(cplx* __restrict__ buf, float scale){
  __shared__ cplx lds[GRID_N];
  cplx* p = buf + (size_t)blockIdx.x * GRID_N;
  int tid = threadIdx.x;                       // 256 threads
  for (int i = tid; i < GRID_N; i += 256){
    int r = __brev((unsigned)i) >> 23;         // 9-bit reverse
    lds[r] = p[i];
  }
  __syncthreads();
  for (int half = 1; half < GRID_N; half <<= 1){
    int j = tid & (half-1);
    int k = ((tid & ~(half-1)) << 1) | j;
    float ang = (float)DIR * 3.14159265358979f * (float)j / (float)half;
    float sw, cw; __sincosf(ang, &sw, &cw);
    cplx u = lds[k];
    cplx v = lds[k+half];
    cplx t; t.x = v.x*cw - v.y*sw; t.y = v.x*sw + v.y*cw;
    lds[k].x      = u.x + t.x; lds[k].y      = u.y + t.y;
    lds[k+half].x = u.x - t.x; lds[k+half].y = u.y - t.y;
    __syncthreads();
  }
  for (int i = tid; i < GRID_N; i += 256){
    cplx v = lds[i]; v.x *= scale; v.y *= scale; p[i] = v;
  }
}

// 512x512 tile transpose per coil plane, out[X][Y] = in[Y][X]
__global__ void k_transpose(const cplx* __restrict__ in, cplx* __restrict__ out){
  __shared__ cplx tile[32][33];
  int c  = blockIdx.z;
  int x0 = blockIdx.x*32, y0 = blockIdx.y*32;
  const cplx* ip = in  + (size_t)c*PLANE;
  cplx*       op = out + (size_t)c*PLANE;
  int tx = threadIdx.x, ty = threadIdx.y;      // (32,8)
  for (int dy = 0; dy < 32; dy += 8)
    tile[ty+dy][tx] = ip[(size_t)(y0+ty+dy)*GRID_N + (x0+tx)];
  __syncthreads();
  for (int dy = 0; dy < 32; dy += 8)
    op[(size_t)(x0+ty+dy)*GRID_N + (y0+tx)] = tile[tx][ty+dy];
}

// planar [c][cell] -> coil-interleaved [cell][8 float2]  (fully coalesced)
__global__ void k_c2i(const float2* __restrict__ plan, float2* __restrict__ inter){
  int t = blockIdx.x*blockDim.x + threadIdx.x;
  if (t >= PLANE*NCOIL) return;
  int c = t & 7; int cell = t >> 3;
  inter[(size_t)cell*8 + c] = plan[(size_t)c*PLANE + cell];
}

// coil-interleaved [cell][8 float2] -> planar [c][cell]
__global__ void k_i2c(const float2* __restrict__ inter, float2* __restrict__ plan){
  int t = blockIdx.x*blockDim.x + threadIdx.x;
  if (t >= PLANE*NCOIL) return;
  int c = t & 7; int cell = t >> 3;
  plan[(size_t)c*PLANE + cell] = inter[(size_t)cell*8 + c];
}

// forward interp + lambda blend: thread = (sample, coil-pair)
__global__ __launch_bounds__(256) void k_fwd(
    const float* __restrict__ ktraj, const float* __restrict__ yre,
    const float* __restrict__ yim, const float* __restrict__ lraw,
    const float4* __restrict__ KTi4, float4* __restrict__ kdc4){
  int t = blockIdx.x*blockDim.x + threadIdx.x;
  if (t >= NK*4) return;
  int k = t >> 2, p = t & 3;

  int iy[JW], ix[JW]; float wy[JW], wx[JW];
  {
    float tm = ktraj[k] * KSCALE;
    int base = (int)floorf(tm - 3.0f);
    #pragma unroll
    for (int j = 1; j <= JW; ++j){
      int fidx = base + j;
      wy[j-1] = kb_w(tm - (float)fidx);
      iy[j-1] = fidx & (GRID_N-1);
    }
  }
  {
    float tm = ktraj[NK + k] * KSCALE;
    int base = (int)floorf(tm - 3.0f);
    #pragma unroll
    for (int j = 1; j <= JW; ++j){
      int fidx = base + j;
      wx[j-1] = kb_w(tm - (float)fidx);
      ix[j-1] = fidx & (GRID_N-1);
    }
  }

  float ax=0.f, ay=0.f, az=0.f, aw=0.f;
  #pragma unroll
  for (int jx = 0; jx < JW; ++jx){
    int ox = ix[jx]*GRID_N;
    #pragma unroll
    for (int jy = 0; jy < JW; ++jy){
      float w2 = wx[jx]*wy[jy];
      float4 v = KTi4[(size_t)(ox + iy[jy])*4 + p];
      ax += w2*v.x; ay += w2*v.y; az += w2*v.z; aw += w2*v.w;
    }
  }
  float lam = 1.0f/(1.0f + __expf(-lraw[0]));
  float oml = 1.0f - lam;
  int c0 = 2*p;
  float4 o;
  o.x = lam*ax + oml*yre[(size_t)c0*NK + k];
  o.y = lam*ay + oml*yim[(size_t)c0*NK + k];
  o.z = lam*az + oml*yre[(size_t)(c0+1)*NK + k];
  o.w = lam*aw + oml*yim[(size_t)(c0+1)*NK + k];
  kdc4[(size_t)k*4 + p] = o;
}

// histogram over x-base classes (512 bins) + per-sample rank
__global__ void k_hist(const float* __restrict__ ktraj, unsigned* __restrict__ hist,
                       unsigned* __restrict__ rank){
  int k = blockIdx.x*blockDim.x + threadIdx.x;
  if (k >= NK) return;
  float tmx = ktraj[NK + k] * KSCALE;
  int bx = (int)floorf(tmx - 3.0f);
  rank[k] = atomicAdd(&hist[bx & (GRID_N-1)], 1u);
}

// per-pair record counts (7-class window) + exclusive scan (1 block, 256 thr)
__global__ void k_scan256(const unsigned* __restrict__ histB, unsigned* __restrict__ pairOff){
  __shared__ unsigned s[256];
  int t = threadIdx.x;
  unsigned v = 0;
  #pragma unroll
  for (int i = 0; i < 7; ++i) v += histB[(2*t - 6 + i) & (GRID_N-1)];
  s[t] = v;
  __syncthreads();
  for (int off = 1; off < 256; off <<= 1){
    unsigned add = (t >= off) ? s[t - off] : 0u;
    __syncthreads();
    s[t] += add;
    __syncthreads();
  }
  pairOff[t] = (t == 0) ? 0u : s[t-1];
  if (t == 255) pairOff[256] = s[255];
}

__device__ __forceinline__ void emit_rec(uint4* __restrict__ recs,
    const unsigned* __restrict__ histB, const unsigned* __restrict__ pairOff,
    int pb, int bxm, unsigned r,
    unsigned pv0, unsigned pv1, unsigned pv2, unsigned pv3,
    unsigned pv4, unsigned pv5, unsigned pv6, unsigned pv7,
    unsigned pw0, unsigned pw1, unsigned pw2,
    float wx0, float wx1, unsigned bym){
  int start = (2*pb - 6) & (GRID_N-1);
  int wlen = (bxm - start) & (GRID_N-1);       // 0..6
  unsigned off = 0;
  for (int i = 0; i < wlen; ++i) off += histB[(start + i) & (GRID_N-1)];
  unsigned pos = pairOff[pb] + off + r;
  uint4* rr = recs + (size_t)pos*4;
  rr[0] = make_uint4(pv0, pv1, pv2, pv3);
  rr[1] = make_uint4(pv4, pv5, pv6, pv7);
  rr[2] = make_uint4(pw0, pw1, pw2, bf16_of(wx0) | (bf16_of(wx1) << 16));
  rr[3] = make_uint4(bym, 0u, 0u, 0u);
}

// build self-contained 64B records per (column-pair, sample):
// { v[16] bf16 (kdc), wy[6] bf16, wx0, wx1 bf16, by } — scan needs NO gathers.
__global__ __launch_bounds__(256) void k_fill_entries2(
    const float* __restrict__ ktraj, const unsigned* __restrict__ rank,
    const unsigned* __restrict__ histB, const unsigned* __restrict__ pairOff,
    const float4* __restrict__ kdc4, uint4* __restrict__ recs){
  int k = blockIdx.x*blockDim.x + threadIdx.x;
  if (k >= NK) return;

  float tmy = ktraj[k] * KSCALE;
  int by = (int)floorf(tmy - 3.0f);
  unsigned bym = (unsigned)(by & (GRID_N-1));
  unsigned pw0, pw1, pw2;
  {
    float w1 = kb_w(tmy-(float)(by+1)), w2 = kb_w(tmy-(float)(by+2));
    float w3 = kb_w(tmy-(float)(by+3)), w4 = kb_w(tmy-(float)(by+4));
    float w5 = kb_w(tmy-(float)(by+5)), w6 = kb_w(tmy-(float)(by+6));
    pw0 = bf16_of(w1) | (bf16_of(w2) << 16);
    pw1 = bf16_of(w3) | (bf16_of(w4) << 16);
    pw2 = bf16_of(w5) | (bf16_of(w6) << 16);
  }
  float4 a0 = kdc4[(size_t)k*4 + 0];
  float4 a1 = kdc4[(size_t)k*4 + 1];
  float4 a2 = kdc4[(size_t)k*4 + 2];
  float4 a3 = kdc4[(size_t)k*4 + 3];
  unsigned pv0 = bf16_of(a0.x) | (bf16_of(a0.y) << 16);
  unsigned pv1 = bf16_of(a0.z) | (bf16_of(a0.w) << 16);
  unsigned pv2 = bf16_of(a1.x) | (bf16_of(a1.y) << 16);
  unsigned pv3 = bf16_of(a1.z) | (bf16_of(a1.w) << 16);
  unsigned pv4 = bf16_of(a2.x) | (bf16_of(a2.y) << 16);
  unsigned pv5 = bf16_of(a2.z) | (bf16_of(a2.w) << 16);
  unsigned pv6 = bf16_of(a3.x) | (bf16_of(a3.y) << 16);
  unsigned pv7 = bf16_of(a3.z) | (bf16_of(a3.w) << 16);

  float tmx = ktraj[NK + k] * KSCALE;
  int bx = (int)floorf(tmx - 3.0f);
  int bxm = bx & (GRID_N-1);
  unsigned r = rank[k];

  int prevPb = -1, curPb = 0;
  float wx0 = 0.f, wx1 = 0.f;
  #pragma unroll
  for (int j = 1; j <= JW; ++j){
    int col = (bx + j) & (GRID_N-1);
    int pb = col >> 1;
    float w = kb_w(tmx - (float)(bx + j));
    if (pb != prevPb){
      if (prevPb >= 0)
        emit_rec(recs, histB, pairOff, curPb, bxm, r,
                 pv0,pv1,pv2,pv3,pv4,pv5,pv6,pv7, pw0,pw1,pw2, wx0,wx1, bym);
      prevPb = pb; curPb = pb; wx0 = 0.f; wx1 = 0.f;
    }
    if (col & 1) wx1 = w; else wx0 = w;
  }
  emit_rec(recs, histB, pairOff, curPb, bxm, r,
           pv0,pv1,pv2,pv3,pv4,pv5,pv6,pv7, pw0,pw1,pw2, wx0,wx1, bym);
}

// adjoint gridding scan: block = (column-pair, q-half), 512 threads.
// Lane (es 0..63, ql 0..7). Pure sequential record stream, zero gathers;
// 12 ds_adds/entry into a 32KB LDS tile acc[2cols][512y][8q].
__global__ __launch_bounds__(512) void k_scan_pair(
    const uint4* __restrict__ recs, const unsigned* __restrict__ pairOff,
    float4* __restrict__ HTi4){
  __shared__ float acc[2*GRID_N*8];            // 32 KB
  const int p = blockIdx.x, h = blockIdx.y;
  const int tid = threadIdx.x;
  const int ql = tid & 7, es = tid >> 3;
  for (int i = tid; i < 2*GRID_N*8; i += 512) acc[i] = 0.f;
  __syncthreads();

  unsigned beg = pairOff[p], end = pairOff[p+1];
  for (unsigned e = beg + es; e < end; e += 64){
    const uint4* r = recs + (size_t)e*4;
    uint4 vh = r[h];                           // my 8 bf16 values
    uint4 wb = r[2];                           // wy0..5, wx0, wx1
    unsigned bym = ((const unsigned*)r)[12];
    // select my bf16 value (static bit-selects, no dynamic indexing)
    unsigned lo = (ql & 4) ? vh.z : vh.x;
    unsigned hi = (ql & 4) ? vh.w : vh.y;
    unsigned word = (ql & 2) ? hi : lo;
    float vq = (ql & 1) ? bf_hi(word) : bf_lo(word);
    float wy0 = bf_lo(wb.x), wy1 = bf_hi(wb.x);
    float wy2 = bf_lo(wb.y), wy3 = bf_hi(wb.y);
    float wy4 = bf_lo(wb.z), wy5 = bf_hi(wb.z);
    float v0 = bf_lo(wb.w) * vq;               // wx0 * v
    float v1 = bf_hi(wb.w) * vq;               // wx1 * v
    int by = (int)bym;
    int y;
    y = (by+1)&(GRID_N-1); atomicAdd(&acc[(y<<3)+ql], wy0*v0); atomicAdd(&acc[4096+(y<<3)+ql], wy0*v1);
    y = (by+2)&(GRID_N-1); atomicAdd(&acc[(y<<3)+ql], wy1*v0); atomicAdd(&acc[4096+(y<<3)+ql], wy1*v1);
    y = (by+3)&(GRID_N-1); atomicAdd(&acc[(y<<3)+ql], wy2*v0); atomicAdd(&acc[4096+(y<<3)+ql], wy2*v1);
    y = (by+4)&(GRID_N-1); atomicAdd(&acc[(y<<3)+ql], wy3*v0); atomicAdd(&acc[4096+(y<<3)+ql], wy3*v1);
    y = (by+5)&(GRID_N-1); atomicAdd(&acc[(y<<3)+ql], wy4*v0); atomicAdd(&acc[4096+(y<<3)+ql], wy4*v1);
    y = (by+6)&(GRID_N-1); atomicAdd(&acc[(y<<3)+ql], wy5*v0); atomicAdd(&acc[4096+(y<<3)+ql], wy5*v1);
  }
  __syncthreads();

  // writeback: cols 2p, 2p+1 ; this block owns float4 slots h*2+{0,1}
  for (int i = tid; i < 2*GRID_N*2; i += 512){
    int colsel = i >> 10;
    int rem = i & 1023;
    int y = rem >> 1, pp = rem & 1;
    int col = 2*p + colsel;
    const float* a = acc + colsel*4096 + (y<<3) + pp*4;
    float4 o = make_float4(a[0], a[1], a[2], a[3]);
    HTi4[((size_t)col*GRID_N + y)*4 + h*2 + pp] = o;
  }
}

// crop, apodize, conj(smaps) coil-combine; ACCUMULATES into out
__global__ void k_final(const cplx* __restrict__ Bg, const float* __restrict__ sr,
                        const float* __restrict__ si, const float* __restrict__ sc,
                        float* __restrict__ out, int pairs){
  int idx = blockIdx.x*blockDim.x + threadIdx.x;   // y*256+x
  if (idx >= IM_N*IM_N) return;
  int y = idx >> 8, x = idx & 255;
  float s2 = sc[y]*sc[x];
  float ax = 0.f, ay = 0.f;
  #pragma unroll
  for (int c = 0; c < NCOIL; ++c){
    cplx v = Bg[(size_t)c*PLANE + y*GRID_N + x];
    int gi = (c << 16) | idx;
    float rr = sr[gi], ii = si[gi];
    ax += rr*v.x + ii*v.y;      // conj(s)*v real
    ay += rr*v.y - ii*v.x;      // conj(s)*v imag
  }
  if (pairs){
    out[idx*2]   += ax * s2;
    out[idx*2+1] += ay * s2;
  } else {
    out[idx]     += ax * s2;
  }
}

// ---------------- fallback (round-2 validated fused atomic path) -------------
__global__ void k_gather_scatter_fb(const float* __restrict__ ktraj,
                                    const float* __restrict__ yre,
                                    const float* __restrict__ yim,
                                    const float* __restrict__ lraw,
                                    const cplx* __restrict__ KT,
                                    float* __restrict__ HT){
  int k = blockIdx.x*blockDim.x + threadIdx.x;
  if (k >= NK) return;
  float lam   = 1.0f/(1.0f + __expf(-lraw[0]));
  float omlam = 1.0f - lam;
  int iy[JW], ix[JW]; float wy[JW], wx[JW];
  {
    float tm = ktraj[k] * KSCALE;
    int base = (int)floorf(tm - 3.0f);
    #pragma unroll
    for (int j = 1; j <= JW; ++j){
      wy[j-1] = kb_w(tm - (float)(base+j));
      iy[j-1] = (base+j) & (GRID_N-1);
    }
  }
  {
    float tm = ktraj[NK + k] * KSCALE;
    int base = (int)floorf(tm - 3.0f);
    #pragma unroll
    for (int j = 1; j <= JW; ++j){
      wx[j-1] = kb_w(tm - (float)(base+j));
      ix[j-1] = (base+j) & (GRID_N-1);
    }
  }
  float accx[NCOIL], accy[NCOIL];
  #pragma unroll
  for (int c = 0; c < NCOIL; ++c){ accx[c]=0.f; accy[c]=0.f; }
  #pragma unroll
  for (int jx = 0; jx < JW; ++jx){
    int ox = ix[jx]*GRID_N;
    #pragma unroll
    for (int jy = 0; jy < JW; ++jy){
      float w2 = wx[jx]*wy[jy];
      size_t o = (size_t)(ox + iy[jy]);
      #pragma unroll
      for (int c = 0; c < NCOIL; ++c){
        cplx v = KT[(size_t)c*PLANE + o];
        accx[c] += w2*v.x; accy[c] += w2*v.y;
      }
    }
  }
  float kdx[NCOIL], kdy[NCOIL];
  #pragma unroll
  for (int c = 0; c < NCOIL; ++c){
    kdx[c] = lam*accx[c] + omlam*yre[(size_t)c*NK + k];
    kdy[c] = lam*accy[c] + omlam*yim[(size_t)c*NK + k];
  }
  #pragma unroll
  for (int jx = 0; jx < JW; ++jx){
    int ox = ix[jx]*GRID_N;
    #pragma unroll
    for (int jy = 0; jy < JW; ++jy){
      float w2 = wx[jx]*wy[jy];
      size_t o = (size_t)(ox + iy[jy]);
      #pragma unroll
      for (int c = 0; c < NCOIL; ++c){
        float* dst = HT + ((size_t)c*PLANE + o)*2;
        atomicAdd(dst,   w2*kdx[c]);
        atomicAdd(dst+1, w2*kdy[c]);
      }
    }
  }
}

extern "C" void kernel_launch(void* const* d_in, const int* in_sizes, int n_in,
                              void* d_out, int out_size, void* d_ws, size_t ws_size,
                              hipStream_t stream) {
  const float* ximg  = (const float*)d_in[0];
  const float* yre   = (const float*)d_in[1];
  const float* yim   = (const float*)d_in[2];
  const float* sre   = (const float*)d_in[3];
  const float* sim   = (const float*)d_in[4];
  const float* ktraj = (const float*)d_in[5];
  const float* lraw  = (const float*)d_in[6];
  float* out = (float*)d_out;

  char* ws = (char*)d_ws;
  const size_t REG = 16777216;                 // one planar grid: 512*512*8B*8
  int pairs = (out_size >= 2*IM_N*IM_N) ? 1 : 0;

  // primary layout (50.34 MB, unchanged requirement):
  //   R0 [0, REG)      A planar -> kdc (8MB) + rank (0.5MB) -> HTi (scan out)
  //   R1R2 [REG, 3REG) Bb planar / KTi -> records (<=524288 x 64B = 33.55MB)
  //                    -> img planar + img^T (ifft)
  //   [3REG, ...)      sc (4KB), histB 512 u32 (2KB), pairOff 257 u32 (2KB)
  const size_t need = 3*REG + 4096 + 2048 + 2048;

  if (ws_size >= need){
    cplx*     A     = (cplx*)ws;                           // R0
    cplx*     Bb    = (cplx*)(ws + REG);                   // R1
    float4*   KTi4  = (float4*)(ws + 2*REG);               // R2
    float*    sc    = (float*)(ws + 3*REG);
    unsigned* histB = (unsigned*)(ws + 3*REG + 4096);
    unsigned* pairOff=(unsigned*)(ws + 3*REG + 4096 + 2048);
    float4*   kdc4  = (float4*)ws;                         // overlays dead A
    unsigned* rank  = (unsigned*)(ws + (size_t)NK*16*4);   // R0 + 8MB
    uint4*    recs  = (uint4*)(ws + REG);                  // R1R2 (33.55MB)
    float4*   HTi4  = (float4*)ws;                         // R0 (after records)
    cplx*     img1  = (cplx*)(ws + REG);                   // R1 (after scan)
    cplx*     img2  = (cplx*)(ws + 2*REG);                 // R2

    const int n4 = NCOIL*PLANE*2/4;

    k_sc_table<<<1,256,0,stream>>>(sc);
    k_zero4<<<(n4+255)/256,256,0,stream>>>((float4*)A, n4);
    k_fill<<<(NCOIL*IM_N*IM_N+255)/256,256,0,stream>>>(ximg, sre, sim, sc, A);

    // fwd fft2/512: rows over x, transpose, rows over y -> Bb = kg^T planar [x][y]
    k_fft_rows<-1><<<NCOIL*GRID_N,256,0,stream>>>(A, 1.0f);
    k_transpose<<<dim3(16,16,NCOIL),dim3(32,8),0,stream>>>(A, Bb);
    k_fft_rows<-1><<<NCOIL*GRID_N,256,0,stream>>>(Bb, 1.0f/(float)GRID_N);

    k_c2i<<<(PLANE*NCOIL+255)/256,256,0,stream>>>((const float2*)Bb, (float2*)KTi4);

    // forward interp + blend -> kdc (overlays dead A region)
    k_fwd<<<(NK*4+255)/256,256,0,stream>>>(ktraj, yre, yim, lraw, KTi4, kdc4);

    // binning: 512-class histogram + per-pair offsets
    k_zero1<<<2,256,0,stream>>>((float*)histB, GRID_N);
    k_hist<<<NK/256,256,0,stream>>>(ktraj, histB, rank);
    k_scan256<<<1,256,0,stream>>>(histB, pairOff);

    // build self-contained records (random STORES, contiguous loads)
    k_fill_entries2<<<NK/256,256,0,stream>>>(ktraj, rank, histB, pairOff,
                                             kdc4, recs);

    // adjoint gridding: pure streaming scan, 256 pairs x 2 q-halves
    k_scan_pair<<<dim3(256,2),512,0,stream>>>(recs, pairOff, HTi4);

    k_i2c<<<(PLANE*NCOIL+255)/256,256,0,stream>>>((const float2*)HTi4, (float2*)img1);

    // adjoint ifft2*512: rows over y, transpose, rows over x -> img2 = img [y][x]
    k_fft_rows<+1><<<NCOIL*GRID_N,256,0,stream>>>(img1, 1.0f);
    k_transpose<<<dim3(16,16,NCOIL),dim3(32,8),0,stream>>>(img1, img2);
    k_fft_rows<+1><<<NCOIL*GRID_N,256,0,stream>>>(img2, 1.0f/(float)GRID_N);

    k_zero1<<<(out_size+255)/256,256,0,stream>>>(out, out_size);
    k_final<<<(IM_N*IM_N+255)/256,256,0,stream>>>(img2, sre, sim, sc, out, pairs);
  } else {
    // fallback: round-2 validated path (needs 33.6 MB)
    float* sc = (float*)ws;
    cplx*  A  = (cplx*)(ws + 4096);
    cplx*  Bb = (cplx*)(ws + 4096 + REG);
    const int n4 = NCOIL*PLANE*2/4;

    k_sc_table<<<1,256,0,stream>>>(sc);
    k_zero4<<<(n4+255)/256,256,0,stream>>>((float4*)A, n4);
    k_fill<<<(NCOIL*IM_N*IM_N+255)/256,256,0,stream>>>(ximg, sre, sim, sc, A);
    k_fft_rows<-1><<<NCOIL*GRID_N,256,0,stream>>>(A, 1.0f);
    k_transpose<<<dim3(16,16,NCOIL),dim3(32,8),0,stream>>>(A, Bb);
    k_fft_rows<-1><<<NCOIL*GRID_N,256,0,stream>>>(Bb, 1.0f/(float)GRID_N);
    k_zero4<<<(n4+255)/256,256,0,stream>>>((float4*)A, n4);
    k_gather_scatter_fb<<<(NK+255)/256,256,0,stream>>>(ktraj, yre, yim, lraw, Bb, (float*)A);
    k_fft_rows<+1><<<NCOIL*GRID_N,256,0,stream>>>(A, 1.0f);
    k_transpose<<<dim3(16,16,NCOIL),dim3(32,8),0,stream>>>(A, Bb);
    k_fft_rows<+1><<<NCOIL*GRID_N,256,0,stream>>>(Bb, 1.0f/(float)GRID_N);
    k_zero1<<<(out_size+255)/256,256,0,stream>>>(out, out_size);
    k_final<<<(IM_N*IM_N+255)/256,256,0,stream>>>(Bb, sre, sim, sc, out, pairs);
  }
}

// Round 10
// 933.933 us; speedup vs baseline: 2.0138x; 2.0138x over previous
//
#include <hip/hip_runtime.h>
#include <math.h>

#define GRID_N 512
#define IM_N   256
#define NCOIL  8
#define NK     131072
#define PLANE  (GRID_N*GRID_N)
#define JW     6
#define NBIN   (GRID_N*GRID_N/512*512)  /* 262144 (col,by) bins */
#define BETA_F 13.8551003f   /* pi*sqrt((6/2)^2*(2-0.5)^2 - 0.8) */
#define KSCALE 81.48733086305042f  /* 512/(2*pi) */

struct cplx { float x, y; };

__device__ __forceinline__ float bessel_i0f(float x){
  // Abramowitz & Stegun 9.8.1 / 9.8.2, rel err < 2e-7
  if (x < 3.75f){
    float t = x*(1.0f/3.75f); t = t*t;
    return 1.0f + t*(3.5156229f + t*(3.0899424f + t*(1.2067492f
           + t*(0.2659732f + t*(0.0360768f + t*0.0045813f)))));
  } else {
    float t = 3.75f/x;
    float p = 0.39894228f + t*(0.01328592f + t*(0.00225319f + t*(-0.00157565f
            + t*(0.00916281f + t*(-0.02057706f + t*(0.02635537f
            + t*(-0.01647633f + t*0.00392377f)))))));
    return p * __expf(x) * rsqrtf(x);
  }
}

__device__ __forceinline__ float kb_w(float u){   // 1-axis KB weight, |u|<=3
  float uu = u*(1.0f/3.0f);
  float q = fmaxf(1.0f - uu*uu, 0.0f);
  return bessel_i0f(BETA_F*sqrtf(q)) * (1.0f/6.0f);
}

__device__ __forceinline__ unsigned bf16_of(float f){
  unsigned u = __float_as_uint(f);
  return (u + 0x8000u) >> 16;
}
__device__ __forceinline__ float bf_lo(unsigned w){ return __uint_as_float(w << 16); }
__device__ __forceinline__ float bf_hi(unsigned w){ return __uint_as_float(w & 0xFFFF0000u); }

// Kaiser-Bessel apodization correction row table sc[256]
__global__ void k_sc_table(float* sc){
  int i = threadIdx.x;
  if (i >= IM_N) return;
  float n  = (i - IM_N*0.5f) * (1.0f/GRID_N);
  float pj = 3.14159265358979f * (float)JW * n;
  float t  = BETA_F*BETA_F - pj*pj;
  float sp = sqrtf(fmaxf(t, 1e-12f));
  float sn = sqrtf(fmaxf(-t, 1e-12f));
  float ft = (t > 0.0f) ? (sinhf(sp)/sp) : (sinf(sn)/sn);
  float sc0 = sinhf(BETA_F)/BETA_F;
  sc[i] = sc0/ft;
}

__global__ void k_zero4(float4* p, int n4){
  int i = blockIdx.x*blockDim.x + threadIdx.x;
  if (i < n4) p[i] = make_float4(0.f,0.f,0.f,0.f);
}

__global__ void k_zero1(float* p, int n){
  int i = blockIdx.x*blockDim.x + threadIdx.x;
  if (i < n) p[i] = 0.f;
}

// coil_images * sc2 into padded 512^2 planar grids (A zeroed beforehand)
__global__ void k_fill(const float* __restrict__ ximg, const float* __restrict__ sr,
                       const float* __restrict__ si, const float* __restrict__ sc,
                       cplx* __restrict__ A){
  int idx = blockIdx.x*blockDim.x + threadIdx.x;   // c*65536 + y*256 + x
  if (idx >= NCOIL*IM_N*IM_N) return;
  int c = idx >> 16;
  int pix = idx & 65535;
  int y = pix >> 8, x = pix & 255;
  float v = ximg[pix] * sc[y]*sc[x];
  cplx o; o.x = v * sr[idx]; o.y = v * si[idx];
  A[(size_t)c*PLANE + y*GRID_N + x] = o;
}

// in-place 512-pt radix-2 FFT on each contiguous row; DIR=-1 fwd, +1 inv(unnorm)
template<int DIR>
__global__ void k_fft_rows(cplx* __restrict__ buf, float scale){
  __shared__ cplx lds[GRID_N];
  cplx* p = buf + (size_t)blockIdx.x * GRID_N;
  int tid = threadIdx.x;                       // 256 threads
  for (int i = tid; i < GRID_N; i += 256){
    int r = __brev((unsigned)i) >> 23;         // 9-bit reverse
    lds[r] = p[i];
  }
  __syncthreads();
  for (int half = 1; half < GRID_N; half <<= 1){
    int j = tid & (half-1);
    int k = ((tid & ~(half-1)) << 1) | j;
    float ang = (float)DIR * 3.14159265358979f * (float)j / (float)half;
    float sw, cw; __sincosf(ang, &sw, &cw);
    cplx u = lds[k];
    cplx v = lds[k+half];
    cplx t; t.x = v.x*cw - v.y*sw; t.y = v.x*sw + v.y*cw;
    lds[k].x      = u.x + t.x; lds[k].y      = u.y + t.y;
    lds[k+half].x = u.x - t.x; lds[k+half].y = u.y - t.y;
    __syncthreads();
  }
  for (int i = tid; i < GRID_N; i += 256){
    cplx v = lds[i]; v.x *= scale; v.y *= scale; p[i] = v;
  }
}

// 512x512 tile transpose per coil plane, out[X][Y] = in[Y][X]
__global__ void k_transpose(const cplx* __restrict__ in, cplx* __restrict__ out){
  __shared__ cplx tile[32][33];
  int c  = blockIdx.z;
  int x0 = blockIdx.x*32, y0 = blockIdx.y*32;
  const cplx* ip = in  + (size_t)c*PLANE;
  cplx*       op = out + (size_t)c*PLANE;
  int tx = threadIdx.x, ty = threadIdx.y;      // (32,8)
  for (int dy = 0; dy < 32; dy += 8)
    tile[ty+dy][tx] = ip[(size_t)(y0+ty+dy)*GRID_N + (x0+tx)];
  __syncthreads();
  for (int dy = 0; dy < 32; dy += 8)
    op[(size_t)(x0+ty+dy)*GRID_N + (y0+tx)] = tile[tx][ty+dy];
}

// planar [c][cell] -> coil-interleaved [cell][8 float2]  (fully coalesced)
__global__ void k_c2i(const float2* __restrict__ plan, float2* __restrict__ inter){
  int t = blockIdx.x*blockDim.x + threadIdx.x;
  if (t >= PLANE*NCOIL) return;
  int c = t & 7; int cell = t >> 3;
  inter[(size_t)cell*8 + c] = plan[(size_t)c*PLANE + cell];
}

// coil-interleaved [cell][8 float2] -> planar [c][cell]
__global__ void k_i2c(const float2* __restrict__ inter, float2* __restrict__ plan){
  int t = blockIdx.x*blockDim.x + threadIdx.x;
  if (t >= PLANE*NCOIL) return;
  int c = t & 7; int cell = t >> 3;
  plan[(size_t)c*PLANE + cell] = inter[(size_t)cell*8 + c];
}

// forward interp + lambda blend: thread = (sample, coil-pair)
__global__ __launch_bounds__(256) void k_fwd(
    const float* __restrict__ ktraj, const float* __restrict__ yre,
    const float* __restrict__ yim, const float* __restrict__ lraw,
    const float4* __restrict__ KTi4, float4* __restrict__ kdc4){
  int t = blockIdx.x*blockDim.x + threadIdx.x;
  if (t >= NK*4) return;
  int k = t >> 2, p = t & 3;

  int iy[JW], ix[JW]; float wy[JW], wx[JW];
  {
    float tm = ktraj[k] * KSCALE;
    int base = (int)floorf(tm - 3.0f);
    #pragma unroll
    for (int j = 1; j <= JW; ++j){
      int fidx = base + j;
      wy[j-1] = kb_w(tm - (float)fidx);
      iy[j-1] = fidx & (GRID_N-1);
    }
  }
  {
    float tm = ktraj[NK + k] * KSCALE;
    int base = (int)floorf(tm - 3.0f);
    #pragma unroll
    for (int j = 1; j <= JW; ++j){
      int fidx = base + j;
      wx[j-1] = kb_w(tm - (float)fidx);
      ix[j-1] = fidx & (GRID_N-1);
    }
  }

  float ax=0.f, ay=0.f, az=0.f, aw=0.f;
  #pragma unroll
  for (int jx = 0; jx < JW; ++jx){
    int ox = ix[jx]*GRID_N;
    #pragma unroll
    for (int jy = 0; jy < JW; ++jy){
      float w2 = wx[jx]*wy[jy];
      float4 v = KTi4[(size_t)(ox + iy[jy])*4 + p];
      ax += w2*v.x; ay += w2*v.y; az += w2*v.z; aw += w2*v.w;
    }
  }
  float lam = 1.0f/(1.0f + __expf(-lraw[0]));
  float oml = 1.0f - lam;
  int c0 = 2*p;
  float4 o;
  o.x = lam*ax + oml*yre[(size_t)c0*NK + k];
  o.y = lam*ay + oml*yim[(size_t)c0*NK + k];
  o.z = lam*az + oml*yre[(size_t)(c0+1)*NK + k];
  o.w = lam*aw + oml*yim[(size_t)(c0+1)*NK + k];
  kdc4[(size_t)k*4 + p] = o;
}

// 2D histogram over (column, y-base-class) bins
__global__ void k_hist2(const float* __restrict__ ktraj, unsigned* __restrict__ hist2){
  int k = blockIdx.x*blockDim.x + threadIdx.x;
  if (k >= NK) return;
  float tmy = ktraj[k] * KSCALE;
  int by = ((int)floorf(tmy - 3.0f)) & (GRID_N-1);
  float tmx = ktraj[NK + k] * KSCALE;
  int bx = (int)floorf(tmx - 3.0f);
  #pragma unroll
  for (int j = 1; j <= JW; ++j){
    int cj = (bx + j) & (GRID_N-1);
    atomicAdd(&hist2[cj*GRID_N + by], 1u);
  }
}

// per-column exclusive scan of 512 by-class counts; emits column totals
__global__ void k_colscan(const unsigned* __restrict__ hist2,
                          unsigned* __restrict__ binOff,
                          unsigned* __restrict__ colTotal){
  __shared__ unsigned s[GRID_N];
  int col = blockIdx.x, t = threadIdx.x;
  unsigned mine = hist2[col*GRID_N + t];
  s[t] = mine;
  __syncthreads();
  for (int off = 1; off < GRID_N; off <<= 1){
    unsigned add = (t >= off) ? s[t - off] : 0u;
    __syncthreads();
    s[t] += add;
    __syncthreads();
  }
  binOff[col*GRID_N + t] = s[t] - mine;        // exclusive within column
  if (t == GRID_N-1) colTotal[col] = s[t];
}

// scan 512 column totals -> column bases (+ grand total at [512])
__global__ void k_scanCT(const unsigned* __restrict__ colTotal,
                         unsigned* __restrict__ colBase){
  __shared__ unsigned s[GRID_N];
  int t = threadIdx.x;
  unsigned mine = colTotal[t];
  s[t] = mine;
  __syncthreads();
  for (int off = 1; off < GRID_N; off <<= 1){
    unsigned add = (t >= off) ? s[t - off] : 0u;
    __syncthreads();
    s[t] += add;
    __syncthreads();
  }
  colBase[t] = s[t] - mine;
  if (t == GRID_N-1) colBase[GRID_N] = s[t];
}

// binOff[i] += colBase[col]; sentinel at NBIN = grand total
__global__ void k_addbase(unsigned* __restrict__ binOff,
                          const unsigned* __restrict__ colBase){
  int i = blockIdx.x*blockDim.x + threadIdx.x;
  if (i > NBIN) return;
  if (i == NBIN){ binOff[i] = colBase[GRID_N]; return; }
  binOff[i] += colBase[i >> 9];
}

// place 16B records binned by (column, by):
// rec = { bf16(wx*wy0)|bf16(wx*wy1)<<16, ..., (kk<<9)|by }
__global__ void k_place(const float* __restrict__ ktraj,
                        const unsigned* __restrict__ binOff,
                        unsigned* __restrict__ cnt2,
                        uint4* __restrict__ recs){
  int k = blockIdx.x*blockDim.x + threadIdx.x;
  if (k >= NK) return;
  float tmy = ktraj[k] * KSCALE;
  int by0 = (int)floorf(tmy - 3.0f);
  int by = by0 & (GRID_N-1);
  float wy[JW];
  #pragma unroll
  for (int j = 1; j <= JW; ++j) wy[j-1] = kb_w(tmy - (float)(by0 + j));

  float tmx = ktraj[NK + k] * KSCALE;
  int bx = (int)floorf(tmx - 3.0f);
  unsigned tag = ((unsigned)k << 9) | (unsigned)by;
  #pragma unroll
  for (int j = 1; j <= JW; ++j){
    int cj = (bx + j) & (GRID_N-1);
    float wx = kb_w(tmx - (float)(bx + j));
    uint4 rec;
    rec.x = bf16_of(wx*wy[0]) | (bf16_of(wx*wy[1]) << 16);
    rec.y = bf16_of(wx*wy[2]) | (bf16_of(wx*wy[3]) << 16);
    rec.z = bf16_of(wx*wy[4]) | (bf16_of(wx*wy[5]) << 16);
    rec.w = tag;
    int bin = cj*GRID_N + by;
    unsigned pos = binOff[bin] + atomicAdd(&cnt2[bin], 1u);
    recs[pos] = rec;
  }
}

// adjoint gridding, atomic-free cell-parallel gather:
// block = (column, coil-quarter qq); thread owns 2 y-cells, float4 regs.
// cell y gathers 6 mini-segments (by = y-1..y-6), FMA in registers.
__global__ __launch_bounds__(256) void k_gather(
    const uint4* __restrict__ recs, const unsigned* __restrict__ binOff,
    const float4* __restrict__ kdc4, float4* __restrict__ HTi4){
  __shared__ unsigned soff[GRID_N + 1];
  const int col = blockIdx.x, qq = blockIdx.y;
  const int tid = threadIdx.x;
  for (int i = tid; i < GRID_N + 1; i += 256)
    soff[i] = binOff[col*GRID_N + i];          // i=512 -> next column start
  __syncthreads();

  for (int y = tid; y < GRID_N; y += 256){
    float ax = 0.f, ay = 0.f, az = 0.f, aw = 0.f;
    #pragma unroll
    for (int j = 1; j <= JW; ++j){
      int b = (y - j) & (GRID_N-1);
      unsigned e = soff[b], ee = soff[b+1];
      for (; e < ee; ++e){
        uint4 rec = recs[e];
        unsigned word = (((j-1)>>1) == 0) ? rec.x : ((((j-1)>>1) == 1) ? rec.y : rec.z);
        float w = ((j-1) & 1) ? bf_hi(word) : bf_lo(word);
        float4 v = kdc4[(size_t)((rec.w >> 9) << 2) + qq];
        ax += w*v.x; ay += w*v.y; az += w*v.z; aw += w*v.w;
      }
    }
    HTi4[((size_t)col*GRID_N + y)*4 + qq] = make_float4(ax, ay, az, aw);
  }
}

// crop, apodize, conj(smaps) coil-combine; ACCUMULATES into out
__global__ void k_final(const cplx* __restrict__ Bg, const float* __restrict__ sr,
                        const float* __restrict__ si, const float* __restrict__ sc,
                        float* __restrict__ out, int pairs){
  int idx = blockIdx.x*blockDim.x + threadIdx.x;   // y*256+x
  if (idx >= IM_N*IM_N) return;
  int y = idx >> 8, x = idx & 255;
  float s2 = sc[y]*sc[x];
  float ax = 0.f, ay = 0.f;
  #pragma unroll
  for (int c = 0; c < NCOIL; ++c){
    cplx v = Bg[(size_t)c*PLANE + y*GRID_N + x];
    int gi = (c << 16) | idx;
    float rr = sr[gi], ii = si[gi];
    ax += rr*v.x + ii*v.y;      // conj(s)*v real
    ay += rr*v.y - ii*v.x;      // conj(s)*v imag
  }
  if (pairs){
    out[idx*2]   += ax * s2;
    out[idx*2+1] += ay * s2;
  } else {
    out[idx]     += ax * s2;
  }
}

// ---------------- fallback (round-2 validated fused atomic path) -------------
__global__ void k_gather_scatter_fb(const float* __restrict__ ktraj,
                                    const float* __restrict__ yre,
                                    const float* __restrict__ yim,
                                    const float* __restrict__ lraw,
                                    const cplx* __restrict__ KT,
                                    float* __restrict__ HT){
  int k = blockIdx.x*blockDim.x + threadIdx.x;
  if (k >= NK) return;
  float lam   = 1.0f/(1.0f + __expf(-lraw[0]));
  float omlam = 1.0f - lam;
  int iy[JW], ix[JW]; float wy[JW], wx[JW];
  {
    float tm = ktraj[k] * KSCALE;
    int base = (int)floorf(tm - 3.0f);
    #pragma unroll
    for (int j = 1; j <= JW; ++j){
      wy[j-1] = kb_w(tm - (float)(base+j));
      iy[j-1] = (base+j) & (GRID_N-1);
    }
  }
  {
    float tm = ktraj[NK + k] * KSCALE;
    int base = (int)floorf(tm - 3.0f);
    #pragma unroll
    for (int j = 1; j <= JW; ++j){
      wx[j-1] = kb_w(tm - (float)(base+j));
      ix[j-1] = (base+j) & (GRID_N-1);
    }
  }
  float accx[NCOIL], accy[NCOIL];
  #pragma unroll
  for (int c = 0; c < NCOIL; ++c){ accx[c]=0.f; accy[c]=0.f; }
  #pragma unroll
  for (int jx = 0; jx < JW; ++jx){
    int ox = ix[jx]*GRID_N;
    #pragma unroll
    for (int jy = 0; jy < JW; ++jy){
      float w2 = wx[jx]*wy[jy];
      size_t o = (size_t)(ox + iy[jy]);
      #pragma unroll
      for (int c = 0; c < NCOIL; ++c){
        cplx v = KT[(size_t)c*PLANE + o];
        accx[c] += w2*v.x; accy[c] += w2*v.y;
      }
    }
  }
  float kdx[NCOIL], kdy[NCOIL];
  #pragma unroll
  for (int c = 0; c < NCOIL; ++c){
    kdx[c] = lam*accx[c] + omlam*yre[(size_t)c*NK + k];
    kdy[c] = lam*accy[c] + omlam*yim[(size_t)c*NK + k];
  }
  #pragma unroll
  for (int jx = 0; jx < JW; ++jx){
    int ox = ix[jx]*GRID_N;
    #pragma unroll
    for (int jy = 0; jy < JW; ++jy){
      float w2 = wx[jx]*wy[jy];
      size_t o = (size_t)(ox + iy[jy]);
      #pragma unroll
      for (int c = 0; c < NCOIL; ++c){
        float* dst = HT + ((size_t)c*PLANE + o)*2;
        atomicAdd(dst,   w2*kdx[c]);
        atomicAdd(dst+1, w2*kdy[c]);
      }
    }
  }
}

extern "C" void kernel_launch(void* const* d_in, const int* in_sizes, int n_in,
                              void* d_out, int out_size, void* d_ws, size_t ws_size,
                              hipStream_t stream) {
  const float* ximg  = (const float*)d_in[0];
  const float* yre   = (const float*)d_in[1];
  const float* yim   = (const float*)d_in[2];
  const float* sre   = (const float*)d_in[3];
  const float* sim   = (const float*)d_in[4];
  const float* ktraj = (const float*)d_in[5];
  const float* lraw  = (const float*)d_in[6];
  float* out = (float*)d_out;

  char* ws = (char*)d_ws;
  const size_t REG = 16777216;                 // one planar grid: 512*512*8B*8
  int pairs = (out_size >= 2*IM_N*IM_N) ? 1 : 0;

  // primary layout (50.34 MB):
  //  R0 [0,REG): A planar -> { kdc 8MB | hist2 1MB | binOff 1MB+4 | cnt2 1MB |
  //              colTotal 2KB | colBase 2052B } -> img1 planar (after gather)
  //  R1 [REG,2REG): Bb planar -> recs (786432 x 16B = 12.6MB) -> img2 planar
  //  R2 [2REG,3REG): KTi interleaved -> HTi (gather output)
  //  [3REG,...): sc (4KB)
  const size_t need = 3*REG + 4096;

  if (ws_size >= need){
    cplx*     A     = (cplx*)ws;                           // R0
    cplx*     Bb    = (cplx*)(ws + REG);                   // R1
    float4*   KTi4  = (float4*)(ws + 2*REG);               // R2
    float*    sc    = (float*)(ws + 3*REG);
    float4*   kdc4  = (float4*)ws;                         // R0 +0   (8MB)
    unsigned* hist2 = (unsigned*)(ws + 8388608);           // R0 +8M  (1MB)
    unsigned* binOff= (unsigned*)(ws + 9437184);           // R0 +9M  (1MB+4)
    unsigned* cnt2  = (unsigned*)(ws + 10534912);          // R0      (1MB)
    unsigned* colTot= (unsigned*)(ws + 11583488);          // 2KB
    unsigned* colBase=(unsigned*)(ws + 11585536);          // 2052B
    uint4*    recs  = (uint4*)(ws + REG);                  // R1 (12.6MB)
    float4*   HTi4  = (float4*)(ws + 2*REG);               // R2 (over dead KTi)
    cplx*     img1  = (cplx*)ws;                           // R0 (after gather)
    cplx*     img2  = (cplx*)(ws + REG);                   // R1 (after ifft rows)

    const int n4 = NCOIL*PLANE*2/4;

    k_sc_table<<<1,256,0,stream>>>(sc);
    k_zero4<<<(n4+255)/256,256,0,stream>>>((float4*)A, n4);
    k_fill<<<(NCOIL*IM_N*IM_N+255)/256,256,0,stream>>>(ximg, sre, sim, sc, A);

    // fwd fft2/512: rows over x, transpose, rows over y -> Bb = kg^T planar [x][y]
    k_fft_rows<-1><<<NCOIL*GRID_N,256,0,stream>>>(A, 1.0f);
    k_transpose<<<dim3(16,16,NCOIL),dim3(32,8),0,stream>>>(A, Bb);
    k_fft_rows<-1><<<NCOIL*GRID_N,256,0,stream>>>(Bb, 1.0f/(float)GRID_N);

    k_c2i<<<(PLANE*NCOIL+255)/256,256,0,stream>>>((const float2*)Bb, (float2*)KTi4);

    // forward interp + blend -> kdc (overlays dead A region)
    k_fwd<<<(NK*4+255)/256,256,0,stream>>>(ktraj, yre, yim, lraw, KTi4, kdc4);

    // (col, by) binning: 2D histogram + hierarchical scan + placement
    k_zero1<<<(NBIN+255)/256,256,0,stream>>>((float*)hist2, NBIN);
    k_zero1<<<(NBIN+255)/256,256,0,stream>>>((float*)cnt2,  NBIN);
    k_hist2<<<NK/256,256,0,stream>>>(ktraj, hist2);
    k_colscan<<<GRID_N,GRID_N,0,stream>>>(hist2, binOff, colTot);
    k_scanCT<<<1,GRID_N,0,stream>>>(colTot, colBase);
    k_addbase<<<(NBIN+256)/256,256,0,stream>>>(binOff, colBase);
    k_place<<<NK/256,256,0,stream>>>(ktraj, binOff, cnt2, recs);

    // atomic-free adjoint gridding: 512 cols x 4 coil-quarters, register FMA
    k_gather<<<dim3(GRID_N,4),256,0,stream>>>(recs, binOff, kdc4, HTi4);

    k_i2c<<<(PLANE*NCOIL+255)/256,256,0,stream>>>((const float2*)HTi4, (float2*)img1);

    // adjoint ifft2*512: rows over y, transpose, rows over x -> img2 = img [y][x]
    k_fft_rows<+1><<<NCOIL*GRID_N,256,0,stream>>>(img1, 1.0f);
    k_transpose<<<dim3(16,16,NCOIL),dim3(32,8),0,stream>>>(img1, img2);
    k_fft_rows<+1><<<NCOIL*GRID_N,256,0,stream>>>(img2, 1.0f/(float)GRID_N);

    k_zero1<<<(out_size+255)/256,256,0,stream>>>(out, out_size);
    k_final<<<(IM_N*IM_N+255)/256,256,0,stream>>>(img2, sre, sim, sc, out, pairs);
  } else {
    // fallback: round-2 validated path (needs 33.6 MB)
    float* sc = (float*)ws;
    cplx*  A  = (cplx*)(ws + 4096);
    cplx*  Bb = (cplx*)(ws + 4096 + REG);
    const int n4 = NCOIL*PLANE*2/4;

    k_sc_table<<<1,256,0,stream>>>(sc);
    k_zero4<<<(n4+255)/256,256,0,stream>>>((float4*)A, n4);
    k_fill<<<(NCOIL*IM_N*IM_N+255)/256,256,0,stream>>>(ximg, sre, sim, sc, A);
    k_fft_rows<-1><<<NCOIL*GRID_N,256,0,stream>>>(A, 1.0f);
    k_transpose<<<dim3(16,16,NCOIL),dim3(32,8),0,stream>>>(A, Bb);
    k_fft_rows<-1><<<NCOIL*GRID_N,256,0,stream>>>(Bb, 1.0f/(float)GRID_N);
    k_zero4<<<(n4+255)/256,256,0,stream>>>((float4*)A, n4);
    k_gather_scatter_fb<<<(NK+255)/256,256,0,stream>>>(ktraj, yre, yim, lraw, Bb, (float*)A);
    k_fft_rows<+1><<<NCOIL*GRID_N,256,0,stream>>>(A, 1.0f);
    k_transpose<<<dim3(16,16,NCOIL),dim3(32,8),0,stream>>>(A, Bb);
    k_fft_rows<+1><<<NCOIL*GRID_N,256,0,stream>>>(Bb, 1.0f/(float)GRID_N);
    k_zero1<<<(out_size+255)/256,256,0,stream>>>(out, out_size);
    k_final<<<(IM_N*IM_N+255)/256,256,0,stream>>>(Bb, sre, sim, sc, out, pairs);
  }
}